// Round 4
// baseline (980.741 us; speedup 1.0000x reference)
//
#include <hip/hip_runtime.h>
#include <hip/hip_bf16.h>
#include <cstdint>

#define DIMc 1024
#define HIDc 2048
#define NTOK 8192
#define NRT 6

typedef __bf16 bf16x8 __attribute__((ext_vector_type(8)));
typedef __bf16 bf16x4 __attribute__((ext_vector_type(4)));
typedef float  f32x4  __attribute__((ext_vector_type(4)));

__device__ __forceinline__ void gl_lds16(const void* gsrc, void* ldst) {
    auto g = (const __attribute__((address_space(1))) void*)gsrc;
    auto l = (__attribute__((address_space(3))) void*)ldst;
    __builtin_amdgcn_global_load_lds(g, l, 16, 0, 0);
}

// ---------------- transpose + fp32->bf16 convert for all weights ----------------
// id 0..15 : w1/w3 of expert ex=id>>1 (half=id&1) -> W13T[ex] rows [half*2048 .. )
// id 16..23: w2 of expert ex=id-16 -> W2T[ex]
// id 24    : out_w -> OutWT
__global__ __launch_bounds__(256) void tcvt_k(
    const float* __restrict__ w1s, const float* __restrict__ w2s, const float* __restrict__ w3s,
    const float* __restrict__ w1r, const float* __restrict__ w2r, const float* __restrict__ w3r,
    const float* __restrict__ outw,
    __bf16* __restrict__ W13T, __bf16* __restrict__ W2T, __bf16* __restrict__ OutWT)
{
    int id = blockIdx.z;
    const float* src; __bf16* dst; int K, N;
    if (id < 16) {
        int ex = id >> 1, half = id & 1;
        const float* w1 = (ex < 2) ? w1s + (size_t)ex * DIMc * HIDc : w1r + (size_t)(ex - 2) * DIMc * HIDc;
        const float* w3 = (ex < 2) ? w3s + (size_t)ex * DIMc * HIDc : w3r + (size_t)(ex - 2) * DIMc * HIDc;
        src = half ? w3 : w1;
        K = 1024; N = 2048;
        dst = W13T + (size_t)ex * 4096 * 1024 + (size_t)half * 2048 * 1024;
    } else if (id < 24) {
        int ex = id - 16;
        src = (ex < 2) ? w2s + (size_t)ex * HIDc * DIMc : w2r + (size_t)(ex - 2) * HIDc * DIMc;
        K = 2048; N = 1024;
        dst = W2T + (size_t)ex * 2048 * 1024;
    } else {
        src = outw; K = 1024; N = 1024; dst = OutWT;
    }
    int n0 = blockIdx.x * 32, k0 = blockIdx.y * 32;
    if (n0 >= N || k0 >= K) return;
    __shared__ float t[32][33];
    int c = threadIdx.x & 31, rb = threadIdx.x >> 5;
#pragma unroll
    for (int i = 0; i < 4; i++) {
        int r = rb + i * 8;
        t[r][c] = src[(size_t)(k0 + r) * N + n0 + c];
    }
    __syncthreads();
#pragma unroll
    for (int i = 0; i < 4; i++) {
        int r = rb + i * 8;  // r = n-offset, c = k-offset (coalesced along k)
        dst[(size_t)(n0 + r) * K + k0 + c] = (__bf16)t[c][r];
    }
}

// ---------------- router: fp32 logits, top-2, aux partials, x->bf16 ----------------
__global__ __launch_bounds__(256) void router_k(
    const float* __restrict__ x, const float* __restrict__ gate,
    __bf16* __restrict__ xb, int* __restrict__ tke, float* __restrict__ tkw,
    float* __restrict__ auxp, float* __restrict__ auxf, int* __restrict__ rcnt)
{
    __shared__ float gl[DIMc * NRT];
    __shared__ float pacc[NRT];
    __shared__ int hist1[NRT], hist2[NRT];
    for (int i = threadIdx.x; i < DIMc * NRT; i += 256) gl[i] = gate[i];
    if (threadIdx.x < NRT) { pacc[threadIdx.x] = 0.f; hist1[threadIdx.x] = 0; hist2[threadIdx.x] = 0; }
    __syncthreads();
    int lane = threadIdx.x & 63, wid = threadIdx.x >> 6;
    for (int rep = 0; rep < 4; rep++) {
        int t = blockIdx.x * 16 + wid * 4 + rep;
        float a[NRT] = {0.f, 0.f, 0.f, 0.f, 0.f, 0.f};
        const float* xr = x + (size_t)t * DIMc;
        __bf16* xbr = xb + (size_t)t * DIMc;
        for (int k = lane; k < DIMc; k += 64) {
            float v = xr[k];
            xbr[k] = (__bf16)v;
#pragma unroll
            for (int e = 0; e < NRT; e++) a[e] += v * gl[k * NRT + e];
        }
#pragma unroll
        for (int e = 0; e < NRT; e++)
#pragma unroll
            for (int m = 32; m; m >>= 1) a[e] += __shfl_xor(a[e], m);
        if (lane == 0) {
            int i0 = 0; float m0 = a[0];
#pragma unroll
            for (int e = 1; e < NRT; e++) if (a[e] > m0) { m0 = a[e]; i0 = e; }
            int i1 = -1; float m1 = -1e30f;
#pragma unroll
            for (int e = 0; e < NRT; e++) if (e != i0 && a[e] > m1) { m1 = a[e]; i1 = e; }
            float w1 = __expf(m1 - m0);
            float inv = 1.f / (1.f + w1);
            tke[2 * t] = i0; tke[2 * t + 1] = i1;
            tkw[2 * t] = inv; tkw[2 * t + 1] = w1 * inv;
            float se = 0.f, pe[NRT];
#pragma unroll
            for (int e = 0; e < NRT; e++) { pe[e] = __expf(a[e] - m0); se += pe[e]; }
            float rinv = 1.f / se;
#pragma unroll
            for (int e = 0; e < NRT; e++) atomicAdd(&pacc[e], pe[e] * rinv);
            atomicAdd(&hist1[i0], 1);
            atomicAdd(&hist2[i0], 1); atomicAdd(&hist2[i1], 1);
        }
    }
    __syncthreads();
    if (threadIdx.x < NRT) {
        atomicAdd(&auxp[threadIdx.x], pacc[threadIdx.x]);
        atomicAdd(&auxf[threadIdx.x], (float)hist1[threadIdx.x]);
        atomicAdd(&rcnt[threadIdx.x], hist2[threadIdx.x]);
    }
}

__global__ void offsets_k(const int* __restrict__ rcnt, int* __restrict__ goff, int* __restrict__ gcnt) {
    if (threadIdx.x == 0) {
        goff[0] = 0; goff[1] = NTOK; gcnt[0] = NTOK; gcnt[1] = NTOK;
        int off = 0;
        for (int e = 0; e < NRT; e++) { goff[2 + e] = off; gcnt[2 + e] = rcnt[e]; off += rcnt[e]; }
    }
}

__global__ __launch_bounds__(256) void scatter_k(
    const int* __restrict__ tke, const float* __restrict__ tkw,
    const int* __restrict__ goff, int* __restrict__ curs,
    int* __restrict__ perm, float* __restrict__ wrow)
{
    int t = blockIdx.x * 256 + threadIdx.x;
    if (t >= NTOK) return;
    perm[t] = t;        wrow[t] = 1.f;          // shared expert 0 (identity)
    perm[NTOK + t] = t; wrow[NTOK + t] = 1.f;   // shared expert 1
#pragma unroll
    for (int k = 0; k < 2; k++) {
        int e = tke[2 * t + k]; float w = tkw[2 * t + k];
        int slot = atomicAdd(&curs[e], 1);
        int pos = 2 * NTOK + goff[2 + e] + slot;
        perm[pos] = t; wrow[pos] = w;
    }
}

__global__ void auxfin_k(const float* __restrict__ auxp, const float* __restrict__ auxf, float* __restrict__ out) {
    if (threadIdx.x == 0) {
        float s = 0.f;
        for (int e = 0; e < NRT; e++) s += (auxf[e] * (1.f / NTOK)) * (auxp[e] * (1.f / NTOK));
        out[(size_t)NTOK * DIMc] = 0.01f * 6.f * s;
    }
}

// ---------------- tiled MFMA GEMM, 128x128 tile, BK=64, 4 waves ----------------
// MODE 0: H13 dual-GEMM  (A = x_bf16 gathered via perm, B = W13T[g]; epilogue silu(h1)*h3 -> g_buf bf16)
// MODE 1: W2             (A = g_buf direct,              B = W2T[g];  epilogue atomicAdd w*val -> combined)
// MODE 2: out-proj       (A = combined_bf16,             B = OutWT;   epilogue store -> d_out)
template <int MODE>
__global__ __launch_bounds__(256, 2) void gemm_k(
    const __bf16* __restrict__ A, const __bf16* __restrict__ Bbase,
    float* __restrict__ outF, __bf16* __restrict__ outB,
    const int* __restrict__ goff, const int* __restrict__ gcnt,
    const int* __restrict__ perm, const float* __restrict__ wrow,
    int gbase, int pbase, int K)
{
    constexpr int NT = (MODE == 0) ? 3 : 2;
    __shared__ __bf16 lds[NT * 128 * 64];
    __bf16* As  = lds;
    __bf16* B1s = lds + 128 * 64;
    __bf16* B3s = (MODE == 0) ? lds + 2 * 128 * 64 : lds;

    const int g = gbase + blockIdx.z;
    const int cnt = gcnt[g];
    const int bx = blockIdx.x, by = blockIdx.y;
    if (bx * 128 >= cnt) return;
    const int gofs = goff[g];
    const int tid = threadIdx.x;
    const int lane = tid & 63, wid = tid >> 6;
    const int wr = wid >> 1, wc = wid & 1;
    const int l15 = lane & 15, l4 = lane >> 4;

    const __bf16* Bg;
    if constexpr (MODE == 0)      Bg = Bbase + (size_t)g * (4096 * 1024);
    else if constexpr (MODE == 1) Bg = Bbase + (size_t)g * (2048 * 1024);
    else                          Bg = Bbase;

    // Staging bases. Chunk (i*256+tid): row = chunk>>3, 16B-chunk col c = chunk&7.
    // XOR swizzle (both-sides, rule #21): LDS slot (row,c) holds global chunk (row, c ^ (row&7)).
    const __bf16* agA[4]; const __bf16* agB1[4]; const __bf16* agB3[4];
    int ldsOfs[4];
#pragma unroll
    for (int i = 0; i < 4; i++) {
        int chunk = i * 256 + tid;
        int row = chunk >> 3, c8 = chunk & 7;
        int cg = c8 ^ (row & 7);
        int r = bx * 128 + row; if (r > cnt - 1) r = cnt - 1;
        size_t arow;
        if constexpr (MODE == 0)      arow = (size_t)perm[pbase + gofs + r];
        else if constexpr (MODE == 1) arow = (size_t)(gofs + r);
        else                          arow = (size_t)r;
        agA[i] = A + arow * (size_t)K + cg * 8;
        int nr = by * 128 + row;
        agB1[i] = Bg + (size_t)nr * K + cg * 8;
        if constexpr (MODE == 0) agB3[i] = Bg + (size_t)(2048 + nr) * K + cg * 8;
        ldsOfs[i] = chunk * 8;
    }

    f32x4 acc1[4][4], acc3[4][4];
#pragma unroll
    for (int mi = 0; mi < 4; mi++)
#pragma unroll
        for (int ni = 0; ni < 4; ni++)
#pragma unroll
            for (int j = 0; j < 4; j++) { acc1[mi][ni][j] = 0.f; acc3[mi][ni][j] = 0.f; }

    const int nkt = K >> 6;
    for (int kt = 0; kt < nkt; kt++) {
        __syncthreads();   // previous compute done before overwrite
#pragma unroll
        for (int i = 0; i < 4; i++) {
            gl_lds16(agA[i] + kt * 64, &As[ldsOfs[i]]);
            gl_lds16(agB1[i] + kt * 64, &B1s[ldsOfs[i]]);
            if constexpr (MODE == 0) gl_lds16(agB3[i] + kt * 64, &B3s[ldsOfs[i]]);
        }
        asm volatile("s_waitcnt vmcnt(0)" ::: "memory");
        __syncthreads();
#pragma unroll
        for (int kk = 0; kk < 64; kk += 32) {
            bf16x8 av[4];
#pragma unroll
            for (int mi = 0; mi < 4; mi++) {
                int lr = wr * 64 + mi * 16 + l15;
                int cr = ((kk >> 3) + l4) ^ (lr & 7);
                av[mi] = *(const bf16x8*)&As[lr * 64 + cr * 8];
            }
#pragma unroll
            for (int ni = 0; ni < 4; ni++) {
                int lr = wc * 64 + ni * 16 + l15;
                int cr = ((kk >> 3) + l4) ^ (lr & 7);
                bf16x8 bv = *(const bf16x8*)&B1s[lr * 64 + cr * 8];
                if constexpr (MODE == 0) {
                    bf16x8 bv3 = *(const bf16x8*)&B3s[lr * 64 + cr * 8];
#pragma unroll
                    for (int mi = 0; mi < 4; mi++) {
                        acc1[mi][ni] = __builtin_amdgcn_mfma_f32_16x16x32_bf16(av[mi], bv,  acc1[mi][ni], 0, 0, 0);
                        acc3[mi][ni] = __builtin_amdgcn_mfma_f32_16x16x32_bf16(av[mi], bv3, acc3[mi][ni], 0, 0, 0);
                    }
                } else {
#pragma unroll
                    for (int mi = 0; mi < 4; mi++)
                        acc1[mi][ni] = __builtin_amdgcn_mfma_f32_16x16x32_bf16(av[mi], bv, acc1[mi][ni], 0, 0, 0);
                }
            }
        }
    }

    // epilogue: D col = lane&15, row = 4*(lane>>4)+reg  [verified m89/m91]
#pragma unroll
    for (int mi = 0; mi < 4; mi++) {
#pragma unroll
        for (int j = 0; j < 4; j++) {
            int r = bx * 128 + wr * 64 + mi * 16 + l4 * 4 + j;
            if (r < cnt) {
                if constexpr (MODE == 0) {
                    size_t orow = (size_t)(gofs + r) * 2048;
#pragma unroll
                    for (int ni = 0; ni < 4; ni++) {
                        int c = by * 128 + wc * 64 + ni * 16 + l15;
                        float h1 = acc1[mi][ni][j], h3 = acc3[mi][ni][j];
                        float sg = h1 / (1.f + __expf(-h1));
                        outB[orow + c] = (__bf16)(sg * h3);
                    }
                } else if constexpr (MODE == 1) {
                    int pos = pbase + gofs + r;
                    int tok = perm[pos]; float w = wrow[pos];
                    size_t orow = (size_t)tok * 1024;
#pragma unroll
                    for (int ni = 0; ni < 4; ni++) {
                        int c = by * 128 + wc * 64 + ni * 16 + l15;
                        atomicAdd(&outF[orow + c], w * acc1[mi][ni][j]);
                    }
                } else {
                    size_t orow = (size_t)r * 1024;
#pragma unroll
                    for (int ni = 0; ni < 4; ni++) {
                        int c = by * 128 + wc * 64 + ni * 16 + l15;
                        outF[orow + c] = acc1[mi][ni][j];
                    }
                }
            }
        }
    }
}

__global__ __launch_bounds__(256) void cvtcomb_k(const float* __restrict__ c, __bf16* __restrict__ cb) {
    size_t i = (size_t)blockIdx.x * 256 + threadIdx.x;   // 4 elems each
    const float4* s = (const float4*)c;
    float4 v = s[i];
    bf16x4 o; o[0] = (__bf16)v.x; o[1] = (__bf16)v.y; o[2] = (__bf16)v.z; o[3] = (__bf16)v.w;
    ((bf16x4*)cb)[i] = o;
}

extern "C" void kernel_launch(void* const* d_in, const int* in_sizes, int n_in,
                              void* d_out, int out_size, void* d_ws, size_t ws_size,
                              hipStream_t stream) {
    const float* x    = (const float*)d_in[0];
    const float* w1s  = (const float*)d_in[1];
    const float* w2s  = (const float*)d_in[2];
    const float* w3s  = (const float*)d_in[3];
    const float* w1r  = (const float*)d_in[4];
    const float* w2r  = (const float*)d_in[5];
    const float* w3r  = (const float*)d_in[6];
    const float* gate = (const float*)d_in[7];
    const float* outw = (const float*)d_in[8];
    float* out = (float*)d_out;

    char* ws = (char*)d_ws;
    // zero region: [combined fp32 32MB][auxp 8f][auxf 8f][rcnt 8i][curs 8i][pad]
    float* combined = (float*)ws;
    float* auxp = (float*)(ws + 33554432);
    float* auxf = auxp + 8;
    int*   rcnt = (int*)(ws + 33554432 + 64);
    int*   curs = rcnt + 8;
    size_t off = 33554432 + 256;
    __bf16* xb    = (__bf16*)(ws + off); off += 16777216;   // [8192][1024]
    __bf16* W13T  = (__bf16*)(ws + off); off += 67108864;   // 8 x [4096][1024]
    __bf16* W2T   = (__bf16*)(ws + off); off += 33554432;   // 8 x [1024][2048]
    __bf16* OutWT = (__bf16*)(ws + off); off += 2097152;    // [1024][1024]
    __bf16* gbuf  = (__bf16*)(ws + off); off += 67108864;   // [16384][2048]
    __bf16* cb    = gbuf;                                   // alias: cb live only after gbuf dead
    int*   tke  = (int*)(ws + off);   off += 65536;
    float* tkw  = (float*)(ws + off); off += 65536;
    int*   perm = (int*)(ws + off);   off += 131072;
    float* wrow = (float*)(ws + off); off += 131072;
    int*   goffp = (int*)(ws + off);  off += 64;
    int*   gcntp = (int*)(ws + off);  off += 64;

    hipMemsetAsync(d_ws, 0, 33554432 + 256, stream);

    dim3 b256(256);
    tcvt_k<<<dim3(64, 64, 25), b256, 0, stream>>>(w1s, w2s, w3s, w1r, w2r, w3r, outw, W13T, W2T, OutWT);
    router_k<<<dim3(512), b256, 0, stream>>>(x, gate, xb, tke, tkw, auxp, auxf, rcnt);
    offsets_k<<<dim3(1), dim3(64), 0, stream>>>(rcnt, goffp, gcntp);
    scatter_k<<<dim3(32), b256, 0, stream>>>(tke, tkw, goffp, curs, perm, wrow);
    auxfin_k<<<dim3(1), dim3(64), 0, stream>>>(auxp, auxf, out);

    // shared experts (groups 0,1): identity perm at pbase=0
    gemm_k<0><<<dim3(64, 16, 2), b256, 0, stream>>>(xb, W13T, nullptr, gbuf, goffp, gcntp, perm, wrow, 0, 0, 1024);
    gemm_k<1><<<dim3(64, 8, 2),  b256, 0, stream>>>(gbuf, W2T, combined, nullptr, goffp, gcntp, perm, wrow, 0, 0, 2048);
    // routed experts (groups 2..7): gathered perm at pbase=16384, g_buf reused
    gemm_k<0><<<dim3(64, 16, 6), b256, 0, stream>>>(xb, W13T, nullptr, gbuf, goffp, gcntp, perm, wrow, 2, 16384, 1024);
    gemm_k<1><<<dim3(64, 8, 6),  b256, 0, stream>>>(gbuf, W2T, combined, nullptr, goffp, gcntp, perm, wrow, 2, 16384, 2048);

    cvtcomb_k<<<dim3(8192), b256, 0, stream>>>(combined, cb);
    gemm_k<2><<<dim3(64, 8, 1), b256, 0, stream>>>(cb, OutWT, out, nullptr, goffp, gcntp, perm, wrow, 0, 0, 1024);
}

// Round 6
// 934.694 us; speedup vs baseline: 1.0493x; 1.0493x over previous
//
#include <hip/hip_runtime.h>
#include <hip/hip_bf16.h>
#include <cstdint>

#define DIMc 1024
#define HIDc 2048
#define NTOK 8192
#define NRT 6

typedef __bf16 bf16x8 __attribute__((ext_vector_type(8)));
typedef __bf16 bf16x4 __attribute__((ext_vector_type(4)));
typedef __bf16 bf16x2v __attribute__((ext_vector_type(2)));
typedef float  f32x4  __attribute__((ext_vector_type(4)));

#define VMCNT(n) asm volatile("s_waitcnt vmcnt(" #n ")" ::: "memory")
#define RBAR()   asm volatile("s_barrier" ::: "memory")

__device__ __forceinline__ void gl_lds16(const void* gsrc, void* ldst) {
    auto g = (const __attribute__((address_space(1))) void*)gsrc;
    auto l = (__attribute__((address_space(3))) void*)ldst;
    __builtin_amdgcn_global_load_lds(g, l, 16, 0, 0);
}

// T1 bijective XCD swizzle (m204). nwg must be computed from the real grid.
__device__ __forceinline__ void xcd_swz(int lid, int nwg, int gx, int& bx, int& by) {
    int q = nwg >> 3, r = nwg & 7;
    int xcd = lid & 7, idx = lid >> 3;
    int nlid = (xcd < r ? xcd * (q + 1) : r * (q + 1) + (xcd - r) * q) + idx;
    bx = nlid % gx; by = nlid / gx;
}

// ---------------- transpose + fp32->bf16 convert for all weights ----------------
__global__ __launch_bounds__(256) void tcvt_k(
    const float* __restrict__ w1s, const float* __restrict__ w2s, const float* __restrict__ w3s,
    const float* __restrict__ w1r, const float* __restrict__ w2r, const float* __restrict__ w3r,
    const float* __restrict__ outw,
    __bf16* __restrict__ W13T, __bf16* __restrict__ W2T, __bf16* __restrict__ OutWT)
{
    int id = blockIdx.z;
    const float* src; __bf16* dst; int K, N;
    if (id < 16) {
        int ex = id >> 1, half = id & 1;
        const float* w1 = (ex < 2) ? w1s + (size_t)ex * DIMc * HIDc : w1r + (size_t)(ex - 2) * DIMc * HIDc;
        const float* w3 = (ex < 2) ? w3s + (size_t)ex * DIMc * HIDc : w3r + (size_t)(ex - 2) * DIMc * HIDc;
        src = half ? w3 : w1;
        K = 1024; N = 2048;
        dst = W13T + (size_t)ex * 4096 * 1024 + (size_t)half * 2048 * 1024;
    } else if (id < 24) {
        int ex = id - 16;
        src = (ex < 2) ? w2s + (size_t)ex * HIDc * DIMc : w2r + (size_t)(ex - 2) * HIDc * DIMc;
        K = 2048; N = 1024;
        dst = W2T + (size_t)ex * 2048 * 1024;
    } else {
        src = outw; K = 1024; N = 1024; dst = OutWT;
    }
    int n0 = blockIdx.x * 32, k0 = blockIdx.y * 32;
    if (n0 >= N || k0 >= K) return;
    __shared__ float t[32][33];
    int c = threadIdx.x & 31, rb = threadIdx.x >> 5;
#pragma unroll
    for (int i = 0; i < 4; i++) {
        int r = rb + i * 8;
        t[r][c] = src[(size_t)(k0 + r) * N + n0 + c];   // t[k_local][n_local]
    }
    __syncthreads();
    int kp = threadIdx.x & 15, nn = threadIdx.x >> 4;
#pragma unroll
    for (int pass = 0; pass < 2; pass++) {
        int n = nn + pass * 16;
        bf16x2v v; v[0] = (__bf16)t[2 * kp][n]; v[1] = (__bf16)t[2 * kp + 1][n];
        *(bf16x2v*)&dst[(size_t)(n0 + n) * K + k0 + 2 * kp] = v;   // 4B stores
    }
}

// ---------------- router: fp32 logits, top-2, aux partials, x->bf16 ----------------
__global__ __launch_bounds__(256) void router_k(
    const float* __restrict__ x, const float* __restrict__ gate,
    __bf16* __restrict__ xb, int* __restrict__ tke, float* __restrict__ tkw,
    float* __restrict__ auxp, float* __restrict__ auxf, int* __restrict__ rcnt)
{
    __shared__ float gl[DIMc * NRT];
    __shared__ float pacc[NRT];
    __shared__ int hist1[NRT], hist2[NRT];
    for (int i = threadIdx.x; i < DIMc * NRT; i += 256) gl[i] = gate[i];
    if (threadIdx.x < NRT) { pacc[threadIdx.x] = 0.f; hist1[threadIdx.x] = 0; hist2[threadIdx.x] = 0; }
    __syncthreads();
    int lane = threadIdx.x & 63, wid = threadIdx.x >> 6;
    for (int rep = 0; rep < 4; rep++) {
        int t = blockIdx.x * 16 + wid * 4 + rep;
        float a[NRT] = {0.f, 0.f, 0.f, 0.f, 0.f, 0.f};
        const float* xr = x + (size_t)t * DIMc;
        __bf16* xbr = xb + (size_t)t * DIMc;
        for (int k = lane; k < DIMc; k += 64) {
            float v = xr[k];
            xbr[k] = (__bf16)v;
#pragma unroll
            for (int e = 0; e < NRT; e++) a[e] += v * gl[k * NRT + e];
        }
#pragma unroll
        for (int e = 0; e < NRT; e++)
#pragma unroll
            for (int m = 32; m; m >>= 1) a[e] += __shfl_xor(a[e], m);
        if (lane == 0) {
            int i0 = 0; float m0 = a[0];
#pragma unroll
            for (int e = 1; e < NRT; e++) if (a[e] > m0) { m0 = a[e]; i0 = e; }
            int i1 = -1; float m1 = -1e30f;
#pragma unroll
            for (int e = 0; e < NRT; e++) if (e != i0 && a[e] > m1) { m1 = a[e]; i1 = e; }
            float w1 = __expf(m1 - m0);
            float inv = 1.f / (1.f + w1);
            tke[2 * t] = i0; tke[2 * t + 1] = i1;
            tkw[2 * t] = inv; tkw[2 * t + 1] = w1 * inv;
            float se = 0.f, pe[NRT];
#pragma unroll
            for (int e = 0; e < NRT; e++) { pe[e] = __expf(a[e] - m0); se += pe[e]; }
            float rinv = 1.f / se;
#pragma unroll
            for (int e = 0; e < NRT; e++) atomicAdd(&pacc[e], pe[e] * rinv);
            atomicAdd(&hist1[i0], 1);
            atomicAdd(&hist2[i0], 1); atomicAdd(&hist2[i1], 1);
        }
    }
    __syncthreads();
    if (threadIdx.x < NRT) {
        atomicAdd(&auxp[threadIdx.x], pacc[threadIdx.x]);
        atomicAdd(&auxf[threadIdx.x], (float)hist1[threadIdx.x]);
        atomicAdd(&rcnt[threadIdx.x], hist2[threadIdx.x]);
    }
}

__global__ void offsets_k(const int* __restrict__ rcnt, int* __restrict__ goff, int* __restrict__ gcnt) {
    if (threadIdx.x == 0) {
        goff[0] = 0; goff[1] = NTOK; gcnt[0] = NTOK; gcnt[1] = NTOK;
        int off = 0;
        for (int e = 0; e < NRT; e++) { goff[2 + e] = off; gcnt[2 + e] = rcnt[e]; off += rcnt[e]; }
    }
}

__global__ __launch_bounds__(256) void scatter_k(
    const int* __restrict__ tke, const float* __restrict__ tkw,
    const int* __restrict__ goff, int* __restrict__ curs,
    int* __restrict__ perm, float* __restrict__ wrow)
{
    int t = blockIdx.x * 256 + threadIdx.x;
    if (t >= NTOK) return;
    perm[t] = t;        wrow[t] = 1.f;
    perm[NTOK + t] = t; wrow[NTOK + t] = 1.f;
#pragma unroll
    for (int k = 0; k < 2; k++) {
        int e = tke[2 * t + k]; float w = tkw[2 * t + k];
        int slot = atomicAdd(&curs[e], 1);
        int pos = 2 * NTOK + goff[2 + e] + slot;
        perm[pos] = t; wrow[pos] = w;
    }
}

__global__ void auxfin_k(const float* __restrict__ auxp, const float* __restrict__ auxf, float* __restrict__ out) {
    if (threadIdx.x == 0) {
        float s = 0.f;
        for (int e = 0; e < NRT; e++) s += (auxf[e] * (1.f / NTOK)) * (auxp[e] * (1.f / NTOK));
        out[(size_t)NTOK * DIMc] = 0.01f * 6.f * s;
    }
}

// ---------------- MODE0: dual-GEMM silu, 256x128(paired) tile, BK=64, 512 thr, dbuf+counted vmcnt ----------------
__global__ __launch_bounds__(512, 2) void gemm13_k(
    const __bf16* __restrict__ A, const __bf16* __restrict__ Bbase, __bf16* __restrict__ outB,
    const int* __restrict__ goff, const int* __restrict__ gcnt, const int* __restrict__ perm,
    int gbase, int pbase)
{
    __shared__ __bf16 lds[2 * 32768];   // per buf: A 256x64 (16384) | B1 128x64 (8192) | B3 128x64 (8192)
    const int g = gbase + blockIdx.z;
    const int cnt = gcnt[g];
    int bx, by;
    xcd_swz(blockIdx.x + gridDim.x * blockIdx.y, gridDim.x * gridDim.y, gridDim.x, bx, by);
    if (bx * 256 >= cnt) return;
    const int gofs = goff[g];
    const int tid = threadIdx.x;
    const int lane = tid & 63, wid = tid >> 6;
    const int wr = wid >> 1, wc = wid & 1;        // 4 x 2 waves, each 64 rows x 64 cols
    const int l15 = lane & 15, l4 = lane >> 4;

    const __bf16* Bg = Bbase + (size_t)g * (4096 * 1024);

    const __bf16* agA[4]; const __bf16* agB1[2]; const __bf16* agB3[2];
    int ldsA[4], ldsB[2];
#pragma unroll
    for (int i = 0; i < 4; i++) {
        int chunk = i * 512 + tid;                 // 0..2047
        int row = chunk >> 3, cg = (chunk & 7) ^ (row & 7);
        int r = bx * 256 + row; if (r > cnt - 1) r = cnt - 1;
        agA[i] = A + (size_t)perm[pbase + gofs + r] * 1024 + cg * 8;
        ldsA[i] = chunk * 8;
    }
#pragma unroll
    for (int i = 0; i < 2; i++) {
        int chunk = i * 512 + tid;                 // 0..1023
        int row = chunk >> 3, cg = (chunk & 7) ^ (row & 7);
        int nr = by * 128 + row;
        agB1[i] = Bg + (size_t)nr * 1024 + cg * 8;
        agB3[i] = Bg + (size_t)(2048 + nr) * 1024 + cg * 8;
        ldsB[i] = chunk * 8;
    }

#define STAGE13(b, kt) { __bf16* d_ = lds + (b) * 32768; \
    _Pragma("unroll") for (int i_ = 0; i_ < 4; i_++) gl_lds16(agA[i_] + (kt) * 64, d_ + ldsA[i_]); \
    _Pragma("unroll") for (int i_ = 0; i_ < 2; i_++) { \
        gl_lds16(agB1[i_] + (kt) * 64, d_ + 16384 + ldsB[i_]); \
        gl_lds16(agB3[i_] + (kt) * 64, d_ + 24576 + ldsB[i_]); } }

    f32x4 acc1[4][4], acc3[4][4];
#pragma unroll
    for (int mi = 0; mi < 4; mi++)
#pragma unroll
        for (int ni = 0; ni < 4; ni++)
#pragma unroll
            for (int j = 0; j < 4; j++) { acc1[mi][ni][j] = 0.f; acc3[mi][ni][j] = 0.f; }

    const int nkt = 16;   // K=1024
    STAGE13(0, 0);
    for (int kt = 0; kt < nkt; kt++) {
        const int cur = kt & 1;
        if (kt + 1 < nkt) { STAGE13(cur ^ 1, kt + 1); VMCNT(8); }
        else              { VMCNT(0); }
        RBAR();                                    // tile kt resident for all waves
        const __bf16* As  = lds + cur * 32768;
        const __bf16* B1s = As + 16384;
        const __bf16* B3s = As + 24576;
#pragma unroll
        for (int kk = 0; kk < 64; kk += 32) {
            bf16x8 av[4];
#pragma unroll
            for (int mi = 0; mi < 4; mi++) {
                int lr = wr * 64 + mi * 16 + l15;
                int cr = ((kk >> 3) + l4) ^ (lr & 7);
                av[mi] = *(const bf16x8*)&As[lr * 64 + cr * 8];
            }
#pragma unroll
            for (int ni = 0; ni < 4; ni++) {
                int lr = wc * 64 + ni * 16 + l15;
                int cr = ((kk >> 3) + l4) ^ (lr & 7);
                bf16x8 bv1 = *(const bf16x8*)&B1s[lr * 64 + cr * 8];
                bf16x8 bv3 = *(const bf16x8*)&B3s[lr * 64 + cr * 8];
#pragma unroll
                for (int mi = 0; mi < 4; mi++) {
                    acc1[mi][ni] = __builtin_amdgcn_mfma_f32_16x16x32_bf16(av[mi], bv1, acc1[mi][ni], 0, 0, 0);
                    acc3[mi][ni] = __builtin_amdgcn_mfma_f32_16x16x32_bf16(av[mi], bv3, acc3[mi][ni], 0, 0, 0);
                }
            }
        }
        RBAR();                                    // all waves done reading buf[cur]
    }

#pragma unroll
    for (int mi = 0; mi < 4; mi++) {
#pragma unroll
        for (int j = 0; j < 4; j++) {
            int r = bx * 256 + wr * 64 + mi * 16 + l4 * 4 + j;
            if (r < cnt) {
                size_t orow = (size_t)(gofs + r) * 2048;
#pragma unroll
                for (int ni = 0; ni < 4; ni++) {
                    int c = by * 128 + wc * 64 + ni * 16 + l15;
                    float h1 = acc1[mi][ni][j], h3 = acc3[mi][ni][j];
                    float sg = h1 / (1.f + __expf(-h1));
                    outB[orow + c] = (__bf16)(sg * h3);
                }
            }
        }
    }
#undef STAGE13
}

// ---------------- MODE1/MODE2: 128x128 tile, BK=64, 256 thr, dbuf+counted vmcnt ----------------
// MODE 1: A = gbuf (group rows), B = W2T[g], epilogue atomicAdd w*val -> combined
// MODE 2: A = cb, B = OutWT, epilogue store -> out
template <int MODE>
__global__ __launch_bounds__(256, 2) void gemmNN_k(
    const __bf16* __restrict__ A, const __bf16* __restrict__ Bbase,
    float* __restrict__ outF,
    const int* __restrict__ goff, const int* __restrict__ gcnt,
    const int* __restrict__ perm, const float* __restrict__ wrow,
    int gbase, int pbase, int K)
{
    __shared__ __bf16 lds[2 * 16384];   // per buf: A 128x64 | B 128x64
    const int g = gbase + blockIdx.z;
    const int cnt = gcnt[g];
    int bx, by;
    xcd_swz(blockIdx.x + gridDim.x * blockIdx.y, gridDim.x * gridDim.y, gridDim.x, bx, by);
    if (bx * 128 >= cnt) return;
    const int gofs = goff[g];
    const int tid = threadIdx.x;
    const int lane = tid & 63, wid = tid >> 6;
    const int wr = wid >> 1, wc = wid & 1;
    const int l15 = lane & 15, l4 = lane >> 4;

    const __bf16* Bg = (MODE == 1) ? Bbase + (size_t)g * (2048 * 1024) : Bbase;

    const __bf16* agA[4]; const __bf16* agB[4];
    int ldsOf[4];
#pragma unroll
    for (int i = 0; i < 4; i++) {
        int chunk = i * 256 + tid;                 // 0..1023
        int row = chunk >> 3, cg = (chunk & 7) ^ (row & 7);
        int r = bx * 128 + row; if (r > cnt - 1) r = cnt - 1;
        size_t arow = (MODE == 1) ? (size_t)(gofs + r) : (size_t)r;
        agA[i] = A + arow * (size_t)K + cg * 8;
        agB[i] = Bg + (size_t)(by * 128 + row) * K + cg * 8;
        ldsOf[i] = chunk * 8;
    }

#define STAGENN(b, kt) { __bf16* d_ = lds + (b) * 16384; \
    _Pragma("unroll") for (int i_ = 0; i_ < 4; i_++) { \
        gl_lds16(agA[i_] + (kt) * 64, d_ + ldsOf[i_]); \
        gl_lds16(agB[i_] + (kt) * 64, d_ + 8192 + ldsOf[i_]); } }

    f32x4 acc[4][4];
#pragma unroll
    for (int mi = 0; mi < 4; mi++)
#pragma unroll
        for (int ni = 0; ni < 4; ni++)
#pragma unroll
            for (int j = 0; j < 4; j++) acc[mi][ni][j] = 0.f;

    const int nkt = K >> 6;
    STAGENN(0, 0);
    for (int kt = 0; kt < nkt; kt++) {
        const int cur = kt & 1;
        if (kt + 1 < nkt) { STAGENN(cur ^ 1, kt + 1); VMCNT(8); }
        else              { VMCNT(0); }
        RBAR();
        const __bf16* As = lds + cur * 16384;
        const __bf16* Bs = As + 8192;
#pragma unroll
        for (int kk = 0; kk < 64; kk += 32) {
            bf16x8 av[4];
#pragma unroll
            for (int mi = 0; mi < 4; mi++) {
                int lr = wr * 64 + mi * 16 + l15;
                int cr = ((kk >> 3) + l4) ^ (lr & 7);
                av[mi] = *(const bf16x8*)&As[lr * 64 + cr * 8];
            }
#pragma unroll
            for (int ni = 0; ni < 4; ni++) {
                int lr = wc * 64 + ni * 16 + l15;
                int cr = ((kk >> 3) + l4) ^ (lr & 7);
                bf16x8 bv = *(const bf16x8*)&Bs[lr * 64 + cr * 8];
#pragma unroll
                for (int mi = 0; mi < 4; mi++)
                    acc[mi][ni] = __builtin_amdgcn_mfma_f32_16x16x32_bf16(av[mi], bv, acc[mi][ni], 0, 0, 0);
            }
        }
        RBAR();
    }

#pragma unroll
    for (int mi = 0; mi < 4; mi++) {
#pragma unroll
        for (int j = 0; j < 4; j++) {
            int r = bx * 128 + wr * 64 + mi * 16 + l4 * 4 + j;
            if (r < cnt) {
                if constexpr (MODE == 1) {
                    int pos = pbase + gofs + r;
                    int tok = perm[pos]; float w = wrow[pos];
                    size_t orow = (size_t)tok * 1024;
#pragma unroll
                    for (int ni = 0; ni < 4; ni++) {
                        int c = by * 128 + wc * 64 + ni * 16 + l15;
                        atomicAdd(&outF[orow + c], w * acc[mi][ni][j]);
                    }
                } else {
                    size_t orow = (size_t)r * 1024;
#pragma unroll
                    for (int ni = 0; ni < 4; ni++) {
                        int c = by * 128 + wc * 64 + ni * 16 + l15;
                        outF[orow + c] = acc[mi][ni][j];
                    }
                }
            }
        }
    }
#undef STAGENN
}

__global__ __launch_bounds__(256) void cvtcomb_k(const float* __restrict__ c, __bf16* __restrict__ cb) {
    size_t i = (size_t)blockIdx.x * 256 + threadIdx.x;
    const float4* s = (const float4*)c;
    float4 v = s[i];
    bf16x4 o; o[0] = (__bf16)v.x; o[1] = (__bf16)v.y; o[2] = (__bf16)v.z; o[3] = (__bf16)v.w;
    ((bf16x4*)cb)[i] = o;
}

extern "C" void kernel_launch(void* const* d_in, const int* in_sizes, int n_in,
                              void* d_out, int out_size, void* d_ws, size_t ws_size,
                              hipStream_t stream) {
    const float* x    = (const float*)d_in[0];
    const float* w1s  = (const float*)d_in[1];
    const float* w2s  = (const float*)d_in[2];
    const float* w3s  = (const float*)d_in[3];
    const float* w1r  = (const float*)d_in[4];
    const float* w2r  = (const float*)d_in[5];
    const float* w3r  = (const float*)d_in[6];
    const float* gate = (const float*)d_in[7];
    const float* outw = (const float*)d_in[8];
    float* out = (float*)d_out;

    char* ws = (char*)d_ws;
    float* combined = (float*)ws;
    float* auxp = (float*)(ws + 33554432);
    float* auxf = auxp + 8;
    int*   rcnt = (int*)(ws + 33554432 + 64);
    int*   curs = rcnt + 8;
    size_t off = 33554432 + 256;
    __bf16* xb    = (__bf16*)(ws + off); off += 16777216;   // [8192][1024]
    __bf16* W13T  = (__bf16*)(ws + off); off += 67108864;   // 8 x [4096][1024]
    __bf16* W2T   = (__bf16*)(ws + off); off += 33554432;   // 8 x [1024][2048]
    __bf16* OutWT = (__bf16*)(ws + off); off += 2097152;    // [1024][1024]
    __bf16* gbuf  = (__bf16*)(ws + off); off += 67108864;   // [16384][2048]
    __bf16* cb    = gbuf;                                   // alias: cb live only after gbuf dead
    int*   tke  = (int*)(ws + off);   off += 65536;
    float* tkw  = (float*)(ws + off); off += 65536;
    int*   perm = (int*)(ws + off);   off += 131072;
    float* wrow = (float*)(ws + off); off += 131072;
    int*   goffp = (int*)(ws + off);  off += 64;
    int*   gcntp = (int*)(ws + off);  off += 64;

    hipMemsetAsync(d_ws, 0, 33554432 + 256, stream);

    dim3 b256(256), b512(512);
    tcvt_k<<<dim3(64, 64, 25), b256, 0, stream>>>(w1s, w2s, w3s, w1r, w2r, w3r, outw, W13T, W2T, OutWT);
    router_k<<<dim3(512), b256, 0, stream>>>(x, gate, xb, tke, tkw, auxp, auxf, rcnt);
    offsets_k<<<dim3(1), dim3(64), 0, stream>>>(rcnt, goffp, gcntp);
    scatter_k<<<dim3(32), b256, 0, stream>>>(tke, tkw, goffp, curs, perm, wrow);
    auxfin_k<<<dim3(1), dim3(64), 0, stream>>>(auxp, auxf, out);

    // shared experts (groups 0,1): identity perm at pbase=0
    gemm13_k<<<dim3(32, 16, 2), b512, 0, stream>>>(xb, W13T, gbuf, goffp, gcntp, perm, 0, 0);
    gemmNN_k<1><<<dim3(64, 8, 2), b256, 0, stream>>>(gbuf, W2T, combined, goffp, gcntp, perm, wrow, 0, 0, 2048);
    // routed experts (groups 2..7): gathered perm at pbase=16384, gbuf reused
    gemm13_k<<<dim3(32, 16, 6), b512, 0, stream>>>(xb, W13T, gbuf, goffp, gcntp, perm, 2, 2 * NTOK);
    gemmNN_k<1><<<dim3(64, 8, 6), b256, 0, stream>>>(gbuf, W2T, combined, goffp, gcntp, perm, wrow, 2, 2 * NTOK, 2048);

    cvtcomb_k<<<dim3(8192), b256, 0, stream>>>(combined, cb);
    gemmNN_k<2><<<dim3(64, 8, 1), b256, 0, stream>>>(cb, OutWT, out, goffp, gcntp, perm, wrow, 0, 0, 1024);
}

// Round 7
// 865.071 us; speedup vs baseline: 1.1337x; 1.0805x over previous
//
#include <hip/hip_runtime.h>
#include <hip/hip_bf16.h>
#include <cstdint>

#define DIMc 1024
#define HIDc 2048
#define NTOK 8192
#define NRT 6

typedef __bf16 bf16x8 __attribute__((ext_vector_type(8)));
typedef __bf16 bf16x2v __attribute__((ext_vector_type(2)));
typedef float  f32x4  __attribute__((ext_vector_type(4)));

#define VMCNT(n) asm volatile("s_waitcnt vmcnt(" #n ")" ::: "memory")
#define RBAR()   asm volatile("s_barrier" ::: "memory")

__device__ __forceinline__ void gl_lds16(const void* gsrc, void* ldst) {
    auto g = (const __attribute__((address_space(1))) void*)gsrc;
    auto l = (__attribute__((address_space(3))) void*)ldst;
    __builtin_amdgcn_global_load_lds(g, l, 16, 0, 0);
}

// T1 bijective XCD swizzle (m204)
__device__ __forceinline__ void xcd_swz(int lid, int nwg, int gx, int& bx, int& by) {
    int q = nwg >> 3, r = nwg & 7;
    int xcd = lid & 7, idx = lid >> 3;
    int nlid = (xcd < r ? xcd * (q + 1) : r * (q + 1) + (xcd - r) * q) + idx;
    bx = nlid % gx; by = nlid / gx;
}

// ---------------- transpose + fp32->bf16 convert for all weights ----------------
// W13T: rows [0,4096)=w1_s0|w1_s1 cols, [4096,8192)=w3_s0|w3_s1  (shared concat, stride 1024)
//       then per routed e: 4096 rows (h1 2048, h3 2048)
// W2T:  shared [1024][4096] (cols 0..2047 w2_s0, 2048.. w2_s1), then routed 6 x [1024][2048]
__global__ __launch_bounds__(256) void tcvt_k(
    const float* __restrict__ w1s, const float* __restrict__ w2s, const float* __restrict__ w3s,
    const float* __restrict__ w1r, const float* __restrict__ w2r, const float* __restrict__ w3r,
    const float* __restrict__ outw,
    __bf16* __restrict__ W13T, __bf16* __restrict__ W2T, __bf16* __restrict__ OutWT)
{
    int id = blockIdx.z;
    const float* src; __bf16* dst; int K, N; size_t S;
    if (id < 4) {
        int half = id >> 1, ex = id & 1;
        src = (half ? w3s : w1s) + (size_t)ex * DIMc * HIDc;
        K = 1024; N = 2048; S = 1024;
        dst = W13T + ((size_t)half * 4096 + ex * 2048) * 1024;
    } else if (id < 16) {
        int j = id - 4; int ex = j >> 1, half = j & 1;
        src = (half ? w3r : w1r) + (size_t)ex * DIMc * HIDc;
        K = 1024; N = 2048; S = 1024;
        dst = W13T + ((size_t)8192 + ex * 4096 + half * 2048) * 1024;
    } else if (id < 18) {
        int ex = id - 16;
        src = w2s + (size_t)ex * HIDc * DIMc;
        K = 2048; N = 1024; S = 4096;
        dst = W2T + ex * 2048;
    } else if (id < 24) {
        int ex = id - 18;
        src = w2r + (size_t)ex * HIDc * DIMc;
        K = 2048; N = 1024; S = 2048;
        dst = W2T + (size_t)4096 * 1024 + (size_t)ex * 2048 * 1024;
    } else {
        src = outw; K = 1024; N = 1024; S = 1024; dst = OutWT;
    }
    int n0 = blockIdx.x * 32, k0 = blockIdx.y * 32;
    if (n0 >= N || k0 >= K) return;
    __shared__ float t[32][33];
    int c = threadIdx.x & 31, rb = threadIdx.x >> 5;
#pragma unroll
    for (int i = 0; i < 4; i++) {
        int r = rb + i * 8;
        t[r][c] = src[(size_t)(k0 + r) * N + n0 + c];   // t[k_local][n_local]
    }
    __syncthreads();
    int kp = threadIdx.x & 15, nn = threadIdx.x >> 4;
#pragma unroll
    for (int pass = 0; pass < 2; pass++) {
        int n = nn + pass * 16;
        bf16x2v v; v[0] = (__bf16)t[2 * kp][n]; v[1] = (__bf16)t[2 * kp + 1][n];
        *(bf16x2v*)&dst[(size_t)(n0 + n) * S + k0 + 2 * kp] = v;
    }
}

// ---------------- router: fp32 logits, top-2, aux partials, x->bf16 ----------------
__global__ __launch_bounds__(256) void router_k(
    const float* __restrict__ x, const float* __restrict__ gate,
    __bf16* __restrict__ xb, int* __restrict__ tke, float* __restrict__ tkw,
    float* __restrict__ auxp, float* __restrict__ auxf, int* __restrict__ rcnt)
{
    __shared__ float gl[DIMc * NRT];
    __shared__ float pacc[NRT];
    __shared__ int hist1[NRT], hist2[NRT];
    for (int i = threadIdx.x; i < DIMc * NRT; i += 256) gl[i] = gate[i];
    if (threadIdx.x < NRT) { pacc[threadIdx.x] = 0.f; hist1[threadIdx.x] = 0; hist2[threadIdx.x] = 0; }
    __syncthreads();
    int lane = threadIdx.x & 63, wid = threadIdx.x >> 6;
    for (int rep = 0; rep < 4; rep++) {
        int t = blockIdx.x * 16 + wid * 4 + rep;
        float a[NRT] = {0.f, 0.f, 0.f, 0.f, 0.f, 0.f};
        const float* xr = x + (size_t)t * DIMc;
        __bf16* xbr = xb + (size_t)t * DIMc;
        for (int k = lane; k < DIMc; k += 64) {
            float v = xr[k];
            xbr[k] = (__bf16)v;
#pragma unroll
            for (int e = 0; e < NRT; e++) a[e] += v * gl[k * NRT + e];
        }
#pragma unroll
        for (int e = 0; e < NRT; e++)
#pragma unroll
            for (int m = 32; m; m >>= 1) a[e] += __shfl_xor(a[e], m);
        if (lane == 0) {
            int i0 = 0; float m0 = a[0];
#pragma unroll
            for (int e = 1; e < NRT; e++) if (a[e] > m0) { m0 = a[e]; i0 = e; }
            int i1 = -1; float m1 = -1e30f;
#pragma unroll
            for (int e = 0; e < NRT; e++) if (e != i0 && a[e] > m1) { m1 = a[e]; i1 = e; }
            float w1 = __expf(m1 - m0);
            float inv = 1.f / (1.f + w1);
            tke[2 * t] = i0; tke[2 * t + 1] = i1;
            tkw[2 * t] = inv; tkw[2 * t + 1] = w1 * inv;
            float se = 0.f, pe[NRT];
#pragma unroll
            for (int e = 0; e < NRT; e++) { pe[e] = __expf(a[e] - m0); se += pe[e]; }
            float rinv = 1.f / se;
#pragma unroll
            for (int e = 0; e < NRT; e++) atomicAdd(&pacc[e], pe[e] * rinv);
            atomicAdd(&hist1[i0], 1);
            atomicAdd(&hist2[i0], 1); atomicAdd(&hist2[i1], 1);
        }
    }
    __syncthreads();
    if (threadIdx.x < NRT) {
        atomicAdd(&auxp[threadIdx.x], pacc[threadIdx.x]);
        atomicAdd(&auxf[threadIdx.x], (float)hist1[threadIdx.x]);
        atomicAdd(&rcnt[threadIdx.x], hist2[threadIdx.x]);
    }
}

__global__ void offsets_k(const int* __restrict__ rcnt, int* __restrict__ goff, int* __restrict__ gcnt) {
    if (threadIdx.x == 0) {
        int off = 0;
        for (int e = 0; e < NRT; e++) { goff[e] = off; gcnt[e] = rcnt[e]; off += rcnt[e]; }
    }
}

__global__ __launch_bounds__(256) void scatter_k(
    const int* __restrict__ tke, const float* __restrict__ tkw,
    const int* __restrict__ goff, int* __restrict__ curs,
    int* __restrict__ perm, float* __restrict__ wrow, int* __restrict__ islot)
{
    int t = blockIdx.x * 256 + threadIdx.x;
    if (t >= NTOK) return;
#pragma unroll
    for (int k = 0; k < 2; k++) {
        int e = tke[2 * t + k]; float w = tkw[2 * t + k];
        int slot = atomicAdd(&curs[e], 1);
        int sr = goff[e] + slot;            // routed slot row in [0, 16384)
        perm[sr] = t; wrow[sr] = w; islot[2 * t + k] = sr;
    }
}

__global__ void auxfin_k(const float* __restrict__ auxp, const float* __restrict__ auxf, float* __restrict__ out) {
    if (threadIdx.x == 0) {
        float s = 0.f;
        for (int e = 0; e < NRT; e++) s += (auxf[e] * (1.f / NTOK)) * (auxp[e] * (1.f / NTOK));
        out[(size_t)NTOK * DIMc] = 0.01f * 6.f * s;
    }
}

// ---------------- dual-GEMM silu: 256(M)x128(N) tile, BK=64, 512 thr, dbuf + counted vmcnt ----------------
// SHARED=1: concat shared expert (N=4096, h3 at +4096 rows, A row = r, out gbuf stride 4096)
// SHARED=0: routed expert e=blockIdx.z (N=2048, h3 at +2048, A row = perm[gofs+r], out gbuf stride 2048)
template <int SHARED>
__global__ __launch_bounds__(512, 2) void gemm13_k(
    const __bf16* __restrict__ A, const __bf16* __restrict__ W13, __bf16* __restrict__ gbuf,
    const int* __restrict__ goff, const int* __restrict__ gcnt, const int* __restrict__ perm)
{
    __shared__ __bf16 lds[2 * 32768];   // per buf: A 256x64 | B1 128x64 | B3 128x64
    int cnt, gofs, h3ofs, gstride;
    const __bf16* Bg;
    if constexpr (SHARED) {
        cnt = NTOK; gofs = 0; h3ofs = 4096 * 1024; gstride = 4096; Bg = W13;
    } else {
        int e = blockIdx.z;
        cnt = gcnt[e]; gofs = goff[e]; h3ofs = 2048 * 1024; gstride = 2048;
        Bg = W13 + ((size_t)8192 + (size_t)e * 4096) * 1024;
    }
    int bx, by;
    xcd_swz(blockIdx.x + gridDim.x * blockIdx.y, gridDim.x * gridDim.y, gridDim.x, bx, by);
    if (bx * 256 >= cnt) return;
    const int tid = threadIdx.x;
    const int lane = tid & 63, wid = tid >> 6;
    const int wr = wid >> 1, wc = wid & 1;        // 4 x 2 waves, each 64 rows x 64 cols
    const int l15 = lane & 15, l4 = lane >> 4;

    const __bf16* agA[4]; const __bf16* agB1[2]; const __bf16* agB3[2];
    int ldsA[4], ldsB[2];
#pragma unroll
    for (int i = 0; i < 4; i++) {
        int chunk = i * 512 + tid;                 // 0..2047
        int row = chunk >> 3, cg = (chunk & 7) ^ (row & 7);
        int r = bx * 256 + row; if (r > cnt - 1) r = cnt - 1;
        size_t arow = SHARED ? (size_t)r : (size_t)perm[gofs + r];
        agA[i] = A + arow * 1024 + cg * 8;
        ldsA[i] = chunk * 8;
    }
#pragma unroll
    for (int i = 0; i < 2; i++) {
        int chunk = i * 512 + tid;                 // 0..1023
        int row = chunk >> 3, cg = (chunk & 7) ^ (row & 7);
        int nr = by * 128 + row;
        agB1[i] = Bg + (size_t)nr * 1024 + cg * 8;
        agB3[i] = Bg + (size_t)h3ofs + (size_t)nr * 1024 + cg * 8;
        ldsB[i] = chunk * 8;
    }

#define STAGE13(b, kt) { __bf16* d_ = lds + (b) * 32768; \
    _Pragma("unroll") for (int i_ = 0; i_ < 4; i_++) gl_lds16(agA[i_] + (kt) * 64, d_ + ldsA[i_]); \
    _Pragma("unroll") for (int i_ = 0; i_ < 2; i_++) { \
        gl_lds16(agB1[i_] + (kt) * 64, d_ + 16384 + ldsB[i_]); \
        gl_lds16(agB3[i_] + (kt) * 64, d_ + 24576 + ldsB[i_]); } }

    f32x4 acc1[4][4], acc3[4][4];
#pragma unroll
    for (int mi = 0; mi < 4; mi++)
#pragma unroll
        for (int ni = 0; ni < 4; ni++)
#pragma unroll
            for (int j = 0; j < 4; j++) { acc1[mi][ni][j] = 0.f; acc3[mi][ni][j] = 0.f; }

    const int nkt = 16;   // K=1024
    STAGE13(0, 0);
    for (int kt = 0; kt < nkt; kt++) {
        const int cur = kt & 1;
        if (kt + 1 < nkt) { STAGE13(cur ^ 1, kt + 1); VMCNT(8); }
        else              { VMCNT(0); }
        RBAR();
        const __bf16* As  = lds + cur * 32768;
        const __bf16* B1s = As + 16384;
        const __bf16* B3s = As + 24576;
#pragma unroll
        for (int kk = 0; kk < 64; kk += 32) {
            bf16x8 av[4];
#pragma unroll
            for (int mi = 0; mi < 4; mi++) {
                int lr = wr * 64 + mi * 16 + l15;
                int cr = ((kk >> 3) + l4) ^ (lr & 7);
                av[mi] = *(const bf16x8*)&As[lr * 64 + cr * 8];
            }
#pragma unroll
            for (int ni = 0; ni < 4; ni++) {
                int lr = wc * 64 + ni * 16 + l15;
                int cr = ((kk >> 3) + l4) ^ (lr & 7);
                bf16x8 bv1 = *(const bf16x8*)&B1s[lr * 64 + cr * 8];
                bf16x8 bv3 = *(const bf16x8*)&B3s[lr * 64 + cr * 8];
#pragma unroll
                for (int mi = 0; mi < 4; mi++) {
                    acc1[mi][ni] = __builtin_amdgcn_mfma_f32_16x16x32_bf16(av[mi], bv1, acc1[mi][ni], 0, 0, 0);
                    acc3[mi][ni] = __builtin_amdgcn_mfma_f32_16x16x32_bf16(av[mi], bv3, acc3[mi][ni], 0, 0, 0);
                }
            }
        }
        RBAR();
    }

#pragma unroll
    for (int mi = 0; mi < 4; mi++) {
#pragma unroll
        for (int j = 0; j < 4; j++) {
            int r = bx * 256 + wr * 64 + mi * 16 + l4 * 4 + j;
            if (r < cnt) {
                size_t orow = (size_t)(gofs + r) * gstride;
#pragma unroll
                for (int ni = 0; ni < 4; ni++) {
                    int c = by * 128 + wc * 64 + ni * 16 + l15;
                    float h1 = acc1[mi][ni][j], h3 = acc3[mi][ni][j];
                    float sg = h1 / (1.f + __expf(-h1));
                    gbuf[orow + c] = (__bf16)(sg * h3);
                }
            }
        }
    }
#undef STAGE13
}

// ---------------- second/output GEMM: 128x128 tile, BK=64, 256 thr, dbuf + counted vmcnt ----------------
// MODE 0: shared w2  (A=gbuf stride K=4096, out ybuf[r] bf16, no scale)
// MODE 1: routed w2  (e=z: A=gbuf rows gofs+r stride 2048, B+=e*2048*1024, out ybuf[8192+gofs+r]*w bf16)
// MODE 2: out-proj   (A=cb stride 1024, out fp32 d_out)
template <int MODE>
__global__ __launch_bounds__(256, 2) void gemmNN_k(
    const __bf16* __restrict__ A, const __bf16* __restrict__ B,
    __bf16* __restrict__ outB16, float* __restrict__ outF32,
    const float* __restrict__ wrow, const int* __restrict__ goff, const int* __restrict__ gcnt,
    int K)
{
    __shared__ __bf16 lds[2 * 16384];   // per buf: A 128x64 | B 128x64
    int cnt, gofs;
    const __bf16* Bg;
    if constexpr (MODE == 1) {
        int e = blockIdx.z;
        cnt = gcnt[e]; gofs = goff[e];
        Bg = B + (size_t)e * 2048 * 1024;
    } else {
        cnt = NTOK; gofs = 0; Bg = B;
    }
    int bx, by;
    xcd_swz(blockIdx.x + gridDim.x * blockIdx.y, gridDim.x * gridDim.y, gridDim.x, bx, by);
    if (bx * 128 >= cnt) return;
    const int tid = threadIdx.x;
    const int lane = tid & 63, wid = tid >> 6;
    const int wr = wid >> 1, wc = wid & 1;
    const int l15 = lane & 15, l4 = lane >> 4;

    const __bf16* agA[4]; const __bf16* agB[4];
    int ldsOf[4];
#pragma unroll
    for (int i = 0; i < 4; i++) {
        int chunk = i * 256 + tid;                 // 0..1023
        int row = chunk >> 3, cg = (chunk & 7) ^ (row & 7);
        int r = bx * 128 + row; if (r > cnt - 1) r = cnt - 1;
        agA[i] = A + (size_t)(gofs + r) * K + cg * 8;
        agB[i] = Bg + (size_t)(by * 128 + row) * K + cg * 8;
        ldsOf[i] = chunk * 8;
    }

#define STAGENN(b, kt) { __bf16* d_ = lds + (b) * 16384; \
    _Pragma("unroll") for (int i_ = 0; i_ < 4; i_++) { \
        gl_lds16(agA[i_] + (kt) * 64, d_ + ldsOf[i_]); \
        gl_lds16(agB[i_] + (kt) * 64, d_ + 8192 + ldsOf[i_]); } }

    f32x4 acc[4][4];
#pragma unroll
    for (int mi = 0; mi < 4; mi++)
#pragma unroll
        for (int ni = 0; ni < 4; ni++)
#pragma unroll
            for (int j = 0; j < 4; j++) acc[mi][ni][j] = 0.f;

    const int nkt = K >> 6;
    STAGENN(0, 0);
    for (int kt = 0; kt < nkt; kt++) {
        const int cur = kt & 1;
        if (kt + 1 < nkt) { STAGENN(cur ^ 1, kt + 1); VMCNT(8); }
        else              { VMCNT(0); }
        RBAR();
        const __bf16* As = lds + cur * 16384;
        const __bf16* Bs = As + 8192;
#pragma unroll
        for (int kk = 0; kk < 64; kk += 32) {
            bf16x8 av[4];
#pragma unroll
            for (int mi = 0; mi < 4; mi++) {
                int lr = wr * 64 + mi * 16 + l15;
                int cr = ((kk >> 3) + l4) ^ (lr & 7);
                av[mi] = *(const bf16x8*)&As[lr * 64 + cr * 8];
            }
#pragma unroll
            for (int ni = 0; ni < 4; ni++) {
                int lr = wc * 64 + ni * 16 + l15;
                int cr = ((kk >> 3) + l4) ^ (lr & 7);
                bf16x8 bv = *(const bf16x8*)&Bs[lr * 64 + cr * 8];
#pragma unroll
                for (int mi = 0; mi < 4; mi++)
                    acc[mi][ni] = __builtin_amdgcn_mfma_f32_16x16x32_bf16(av[mi], bv, acc[mi][ni], 0, 0, 0);
            }
        }
        RBAR();
    }

#pragma unroll
    for (int mi = 0; mi < 4; mi++) {
#pragma unroll
        for (int j = 0; j < 4; j++) {
            int r = bx * 128 + wr * 64 + mi * 16 + l4 * 4 + j;
            if (r < cnt) {
                if constexpr (MODE == 0) {
                    size_t orow = (size_t)r * 1024;
#pragma unroll
                    for (int ni = 0; ni < 4; ni++) {
                        int c = by * 128 + wc * 64 + ni * 16 + l15;
                        outB16[orow + c] = (__bf16)acc[mi][ni][j];
                    }
                } else if constexpr (MODE == 1) {
                    int sr = gofs + r;
                    float w = wrow[sr];
                    size_t orow = (size_t)(8192 + sr) * 1024;
#pragma unroll
                    for (int ni = 0; ni < 4; ni++) {
                        int c = by * 128 + wc * 64 + ni * 16 + l15;
                        outB16[orow + c] = (__bf16)(w * acc[mi][ni][j]);
                    }
                } else {
                    size_t orow = (size_t)r * 1024;
#pragma unroll
                    for (int ni = 0; ni < 4; ni++) {
                        int c = by * 128 + wc * 64 + ni * 16 + l15;
                        outF32[orow + c] = acc[mi][ni][j];
                    }
                }
            }
        }
    }
#undef STAGENN
}

// ---------------- combine: cb[t] = bf16( ys[t] + yr[islot0] + yr[islot1] ) ----------------
__global__ __launch_bounds__(256) void combine_k(
    const __bf16* __restrict__ ybuf, const int* __restrict__ islot, __bf16* __restrict__ cb)
{
    int tid = threadIdx.x;
    int row = blockIdx.x * 2 + (tid >> 7);
    int c8 = (tid & 127) * 8;
    int s0 = islot[2 * row], s1 = islot[2 * row + 1];
    bf16x8 vs = *(const bf16x8*)&ybuf[(size_t)row * 1024 + c8];
    bf16x8 v0 = *(const bf16x8*)&ybuf[(size_t)(8192 + s0) * 1024 + c8];
    bf16x8 v1 = *(const bf16x8*)&ybuf[(size_t)(8192 + s1) * 1024 + c8];
    bf16x8 o;
#pragma unroll
    for (int j = 0; j < 8; j++) o[j] = (__bf16)((float)vs[j] + (float)v0[j] + (float)v1[j]);
    *(bf16x8*)&cb[(size_t)row * 1024 + c8] = o;
}

extern "C" void kernel_launch(void* const* d_in, const int* in_sizes, int n_in,
                              void* d_out, int out_size, void* d_ws, size_t ws_size,
                              hipStream_t stream) {
    const float* x    = (const float*)d_in[0];
    const float* w1s  = (const float*)d_in[1];
    const float* w2s  = (const float*)d_in[2];
    const float* w3s  = (const float*)d_in[3];
    const float* w1r  = (const float*)d_in[4];
    const float* w2r  = (const float*)d_in[5];
    const float* w3r  = (const float*)d_in[6];
    const float* gate = (const float*)d_in[7];
    const float* outw = (const float*)d_in[8];
    float* out = (float*)d_out;

    char* ws = (char*)d_ws;
    // zeroed counter region (256 B): auxp 8f | auxf 8f | rcnt 8i | curs 8i
    float* auxp = (float*)ws;
    float* auxf = auxp + 8;
    int*   rcnt = (int*)(ws + 64);
    int*   curs = rcnt + 8;
    size_t off = 256;
    __bf16* xb    = (__bf16*)(ws + off); off += 16777216;   // [8192][1024]
    __bf16* W13T  = (__bf16*)(ws + off); off += 67108864;   // 32768 rows x 1024
    __bf16* W2T   = (__bf16*)(ws + off); off += 33554432;   // shared 1024x4096 + 6 x 1024x2048
    __bf16* OutWT = (__bf16*)(ws + off); off += 2097152;    // [1024][1024]
    __bf16* gbuf  = (__bf16*)(ws + off); off += 67108864;   // shared 8192x4096 OR routed 16384x2048 (reused)
    __bf16* cb    = gbuf;                                   // alias: cb live only after gbuf dead
    __bf16* ybuf  = (__bf16*)(ws + off); off += 50331648;   // 24576 rows x 1024 (ys 8192 | yr 16384)
    int*   tke   = (int*)(ws + off);   off += 65536;
    float* tkw   = (float*)(ws + off); off += 65536;
    int*   perm  = (int*)(ws + off);   off += 65536;        // 16384 routed slots
    float* wrow  = (float*)(ws + off); off += 65536;
    int*   islot = (int*)(ws + off);   off += 65536;
    int*   goffp = (int*)(ws + off);   off += 64;
    int*   gcntp = (int*)(ws + off);   off += 64;

    hipMemsetAsync(d_ws, 0, 256, stream);

    dim3 b256(256), b512(512);
    tcvt_k<<<dim3(64, 64, 25), b256, 0, stream>>>(w1s, w2s, w3s, w1r, w2r, w3r, outw, W13T, W2T, OutWT);
    router_k<<<dim3(512), b256, 0, stream>>>(x, gate, xb, tke, tkw, auxp, auxf, rcnt);
    offsets_k<<<dim3(1), dim3(64), 0, stream>>>(rcnt, goffp, gcntp);
    scatter_k<<<dim3(32), b256, 0, stream>>>(tke, tkw, goffp, curs, perm, wrow, islot);
    auxfin_k<<<dim3(1), dim3(64), 0, stream>>>(auxp, auxf, out);

    // shared concat expert: x -> gbuf[8192][4096] -> ys
    gemm13_k<1><<<dim3(32, 32, 1), b512, 0, stream>>>(xb, W13T, gbuf, goffp, gcntp, perm);
    gemmNN_k<0><<<dim3(64, 8, 1), b256, 0, stream>>>(gbuf, W2T, ybuf, nullptr, wrow, goffp, gcntp, 4096);
    // routed experts: x(gathered) -> gbuf[16384][2048] -> yr (scaled)
    gemm13_k<0><<<dim3(32, 16, 6), b512, 0, stream>>>(xb, W13T, gbuf, goffp, gcntp, perm);
    gemmNN_k<1><<<dim3(64, 8, 6), b256, 0, stream>>>(gbuf, W2T + (size_t)4096 * 1024, ybuf, nullptr, wrow, goffp, gcntp, 2048);

    combine_k<<<dim3(4096), b256, 0, stream>>>(ybuf, islot, cb);
    gemmNN_k<2><<<dim3(64, 8, 1), b256, 0, stream>>>(cb, OutWT, nullptr, out, wrow, goffp, gcntp, 1024);
}